// Round 10
// baseline (453.080 us; speedup 1.0000x reference)
//
#include <hip/hip_runtime.h>

static inline int ceil_div(long long a, long long b) { return (int)((a + b - 1) / b); }

typedef __attribute__((ext_vector_type(8))) short bf16x8;
typedef __attribute__((ext_vector_type(4))) float f32x4;

#define TILE 8192          // edges per bucket-pass block
#define BKSH 9             // bucket = dst >> 9  (512 dsts per bucket)

__device__ __forceinline__ float lrelu(float t) { return t > 0.f ? t : 0.2f * t; }

__device__ __forceinline__ void atomAddF(float* p, float v) {
  unsafeAtomicAdd(p, v);  // hardware global_atomic_add_f32
}

// float -> bf16 with round-to-nearest-even
__device__ __forceinline__ unsigned int f2bf(float f) {
  unsigned int u = __float_as_uint(f);
  unsigned int r = ((u >> 16) & 1u) + 0x7fffu;
  return (u + r) >> 16;
}

// ---------------- one-time converts ----------------
__global__ void cvt_bf16(const float* __restrict__ X, unsigned short* __restrict__ Xb, int n4) {
  int i = blockIdx.x * blockDim.x + threadIdx.x;
  if (i < n4) {
    const float4 v = ((const float4*)X)[i];
    uint2 o;
    o.x = f2bf(v.x) | (f2bf(v.y) << 16);
    o.y = f2bf(v.z) | (f2bf(v.w) << 16);
    ((uint2*)Xb)[i] = o;
  }
}

// all three weight transposes in one launch
__global__ void transpose_all(const float* __restrict__ W1, const float* __restrict__ W2,
                              const float* __restrict__ W3, unsigned short* __restrict__ Wt1,
                              unsigned short* __restrict__ Wt2, unsigned short* __restrict__ Wt3) {
  int idx = blockIdx.x * blockDim.x + threadIdx.x;
  const float* W; unsigned short* Wt; int local, DOUTv;
  if (idx < 16384)      { W = W1; Wt = Wt1; local = idx;          DOUTv = 128; }
  else if (idx < 32768) { W = W2; Wt = Wt2; local = idx - 16384;  DOUTv = 128; }
  else if (idx < 40960) { W = W3; Wt = Wt3; local = idx - 32768;  DOUTv = 64;  }
  else return;
  const int k = local / DOUTv, n = local % DOUTv;
  Wt[n * 128 + k] = (unsigned short)f2bf(W[local]);
}

// ---------------- MFMA GEMM + attention scores (CG=2 tile, no spills — R5 design) ----
template<int DOUT>
__launch_bounds__(256)
__global__ void gemm_mfma(const unsigned short* __restrict__ Xb, const unsigned short* __restrict__ Wt,
                          const float* __restrict__ avs, const float* __restrict__ avd,
                          unsigned short* __restrict__ Hb, float* __restrict__ Ss,
                          float* __restrict__ Sd, int N, int RG) {
  constexpr int DIN = 128;
  constexpr int CG = DOUT / 64;
  const int wave = (int)((blockIdx.x * (unsigned)blockDim.x + threadIdx.x) >> 6);
  const int rg = wave / CG;
  const int cg = wave % CG;
  if (rg >= RG) return;
  const int lane = threadIdx.x & 63;
  const int l16 = lane & 15, quad = lane >> 4;
  const int row0 = rg * 64, colw0 = cg * 64;

  int xoff[4], woff[4];
#pragma unroll
  for (int t = 0; t < 4; t++) {
    int m = row0 + t * 16 + l16; if (m > N - 1) m = N - 1;
    xoff[t] = m * DIN + quad * 8;
    woff[t] = (colw0 + t * 16 + l16) * DIN + quad * 8;
  }

  f32x4 acc[4][4];
#pragma unroll
  for (int a = 0; a < 4; a++)
#pragma unroll
    for (int c = 0; c < 4; c++) acc[a][c] = (f32x4)0.f;

#pragma unroll
  for (int kk = 0; kk < 4; kk++) {
    bf16x8 aw[4], bx[4];
#pragma unroll
    for (int t = 0; t < 4; t++) aw[t] = *(const bf16x8*)(Wt + woff[t] + kk * 32);
#pragma unroll
    for (int t = 0; t < 4; t++) bx[t] = *(const bf16x8*)(Xb + xoff[t] + kk * 32);
#pragma unroll
    for (int wt = 0; wt < 4; wt++)
#pragma unroll
      for (int xt = 0; xt < 4; xt++)
        acc[wt][xt] = __builtin_amdgcn_mfma_f32_16x16x32_bf16(aw[wt], bx[xt], acc[wt][xt], 0, 0, 0);
  }

  float4 af[4], df[4];
#pragma unroll
  for (int wt = 0; wt < 4; wt++) {
    af[wt] = *(const float4*)(avs + colw0 + wt * 16 + quad * 4);
    df[wt] = *(const float4*)(avd + colw0 + wt * 16 + quad * 4);
  }
#pragma unroll
  for (int xt = 0; xt < 4; xt++) {
    const int m = row0 + xt * 16 + l16;
    float ps = 0.f, pd = 0.f;
#pragma unroll
    for (int wt = 0; wt < 4; wt++) {
      const f32x4 c = acc[wt][xt];
      ps += c[0]*af[wt].x + c[1]*af[wt].y + c[2]*af[wt].z + c[3]*af[wt].w;
      pd += c[0]*df[wt].x + c[1]*df[wt].y + c[2]*df[wt].z + c[3]*df[wt].w;
    }
    ps += __shfl_xor(ps, 16); ps += __shfl_xor(ps, 32);
    pd += __shfl_xor(pd, 16); pd += __shfl_xor(pd, 32);
    if (quad == 0 && m < N) { atomAddF(&Ss[m], ps); atomAddF(&Sd[m], pd); }
    if (m < N) {
      unsigned short* hp = Hb + (size_t)m * DOUT + colw0 + quad * 4;
#pragma unroll
      for (int wt = 0; wt < 4; wt++) {
        const f32x4 c = acc[wt][xt];
        uint2 o;
        o.x = f2bf(c[0]) | (f2bf(c[1]) << 16);
        o.y = f2bf(c[2]) | (f2bf(c[3]) << 16);
        *(uint2*)(hp + wt * 16) = o;
      }
    }
  }
}

// ---------------- CSR build: bucket sort, zero global atomics ----------------
__launch_bounds__(256)
__global__ void bucket_hist(const int* __restrict__ dstv, int* __restrict__ bh,
                            int E, int NBUK) {
  __shared__ int h[256];
  h[threadIdx.x] = 0;
  __syncthreads();
  const int base = blockIdx.x * TILE;
  const int end = min(E, base + TILE);
  for (int i = base + threadIdx.x; i < end; i += 256)
    atomicAdd(&h[dstv[i] >> BKSH], 1);
  __syncthreads();
  if (threadIdx.x < NBUK) bh[blockIdx.x * NBUK + threadIdx.x] = h[threadIdx.x];
}

__launch_bounds__(256)
__global__ void col_scan(int* __restrict__ bh, int* __restrict__ tot, int NBA, int NBUK) {
  __shared__ int sc[256];
  const int t = threadIdx.x;
  const int b = blockIdx.x;
  int carry = 0;
  for (int c0 = 0; c0 < NBA; c0 += 256) {
    const int idx = c0 + t;
    const int v = (idx < NBA) ? bh[idx * NBUK + b] : 0;
    sc[t] = v;
    __syncthreads();
    for (int off = 1; off < 256; off <<= 1) {
      int u = (t >= off) ? sc[t - off] : 0;
      __syncthreads();
      sc[t] += u;
      __syncthreads();
    }
    if (idx < NBA) bh[idx * NBUK + b] = carry + sc[t] - v;
    carry += sc[255];
    __syncthreads();
  }
  if (t == 0) tot[b] = carry;
}

__launch_bounds__(256)
__global__ void base_scan(const int* __restrict__ tot, int* __restrict__ bucketBase,
                          int* __restrict__ rowptr_N, int NBUK, int E) {
  __shared__ int sc[256];
  const int t = threadIdx.x;
  int carry = 0;
  for (int c0 = 0; c0 < NBUK; c0 += 256) {
    const int idx = c0 + t;
    const int v = (idx < NBUK) ? tot[idx] : 0;
    sc[t] = v;
    __syncthreads();
    for (int off = 1; off < 256; off <<= 1) {
      int u = (t >= off) ? sc[t - off] : 0;
      __syncthreads();
      sc[t] += u;
      __syncthreads();
    }
    if (idx < NBUK) bucketBase[idx] = carry + sc[t] - v;
    carry += sc[255];
    __syncthreads();
  }
  if (t == 0) { bucketBase[NBUK] = E; *rowptr_N = E; }
}

__launch_bounds__(256)
__global__ void bucket_scatter(const int* __restrict__ src, const int* __restrict__ dstv,
                               const int* __restrict__ bh, const int* __restrict__ bucketBase,
                               unsigned int* __restrict__ pairs, int E, int NBUK) {
  __shared__ int ofs[256];
  if (threadIdx.x < NBUK)
    ofs[threadIdx.x] = bh[blockIdx.x * NBUK + threadIdx.x] + bucketBase[threadIdx.x];
  __syncthreads();
  const int base = blockIdx.x * TILE;
  const int end = min(E, base + TILE);
  for (int i = base + threadIdx.x; i < end; i += 256) {
    const int d = dstv[i];
    const int pos = atomicAdd(&ofs[d >> BKSH], 1);
    pairs[pos] = ((unsigned int)src[i] << BKSH) | (unsigned int)(d & ((1 << BKSH) - 1));
  }
}

__launch_bounds__(256)
__global__ void region_build(const unsigned int* __restrict__ pairs,
                             const int* __restrict__ bucketBase,
                             int* __restrict__ rowptr, int* __restrict__ srcs, int N) {
  __shared__ int cnt[512], ofs[512], ps[256];
  const int t = threadIdx.x;
  const int r = blockIdx.x;
  const int p0 = bucketBase[r], p1 = bucketBase[r + 1];
  cnt[t] = 0; cnt[t + 256] = 0;
  __syncthreads();
  for (int i = p0 + t; i < p1; i += 256)
    atomicAdd(&cnt[pairs[i] & 511u], 1);
  __syncthreads();
  const int c0 = cnt[2 * t], c1 = cnt[2 * t + 1];
  const int pr = c0 + c1;
  ps[t] = pr;
  __syncthreads();
  for (int off = 1; off < 256; off <<= 1) {
    int v = (t >= off) ? ps[t - off] : 0;
    __syncthreads();
    ps[t] += v;
    __syncthreads();
  }
  const int pbase = ps[t] - pr;
  ofs[2 * t] = pbase; ofs[2 * t + 1] = pbase + c0;
  __syncthreads();
  {
    const int d0 = (r << BKSH) + t;
    if (d0 < N) rowptr[d0] = p0 + ofs[t];
    const int d1 = (r << BKSH) + t + 256;
    if (d1 < N) rowptr[d1] = p0 + ofs[t + 256];
  }
  __syncthreads();
  for (int i = p0 + t; i < p1; i += 256) {
    const unsigned int w = pairs[i];
    const int pos = atomicAdd(&ofs[w & 511u], 1);
    srcs[p0 + pos] = (int)(w >> BKSH);
  }
}

// ---------------- fused per-dst gather: 16 lanes/node, explicit 8-deep load pipeline --
// __launch_bounds__(256,3) lifts the VGPR cap so the 2x8 in-flight uint4 batches stay
// in registers (R9's VGPR=36 showed the compiler serialized the loads -> MLP ~1.5).
template<int DOUT, bool OBF>
__launch_bounds__(256, 3)
__global__ void node_gather(const int* __restrict__ rowptr, const int* __restrict__ srcs,
                            const float* __restrict__ Ss, const float* __restrict__ Sd,
                            const unsigned short* __restrict__ Hb, const float* __restrict__ b,
                            float* __restrict__ out, unsigned short* __restrict__ outb, int N) {
  constexpr int EPL = DOUT / 16;          // bf16 elems per lane (8 or 4)
  constexpr int CAP = 64;                 // LDS-staged edges per node
  __shared__ uint2 swL[16][CAP + 2];      // +2: bank-conflict padding

  const int l16 = threadIdx.x & 15;
  const int grp = threadIdx.x >> 4;
  const int node = blockIdx.x * 16 + grp;
  if (node >= N) return;

  const int r0 = rowptr[node], r1 = rowptr[node + 1];
  const int deg = r1 - r0;
  const int degc = min(deg, CAP);
  const float sd = Sd[node];
  const float eself = lrelu(Ss[node] + sd);

  float m = eself;
  for (int j0 = 0; j0 < deg; j0 += 16) {
    const int idx = j0 + l16;
    float e = -1e30f;
    if (idx < deg) {
      const int s = srcs[r0 + idx];
      e = lrelu(Ss[s] + sd);
      if (idx < CAP) swL[grp][idx] = make_uint2((unsigned)s, __float_as_uint(e));
    }
    m = fmaxf(m, e);
  }
#pragma unroll
  for (int off = 8; off; off >>= 1) m = fmaxf(m, __shfl_xor(m, off));

  const float wself = __expf(eself - m);
  float lsum = 0.f;
  for (int j0 = 0; j0 < degc; j0 += 16) {
    const int idx = j0 + l16;
    if (idx < degc) {
      uint2 sw = swL[grp][idx];
      const float w = __expf(__uint_as_float(sw.y) - m);
      sw.y = __float_as_uint(w);
      swL[grp][idx] = sw;
      lsum += w;
    }
  }
  for (int j0 = CAP; j0 < deg; j0 += 16) {
    const int idx = j0 + l16;
    if (idx < deg) {
      const int s = srcs[r0 + idx];
      lsum += __expf(lrelu(Ss[s] + sd) - m);
    }
  }
#pragma unroll
  for (int off = 8; off; off >>= 1) lsum += __shfl_xor(lsum, off);
  const float inv = 1.f / (lsum + wself);
  __syncthreads();

  float acc[EPL];
#pragma unroll
  for (int k = 0; k < EPL; k++) acc[k] = 0.f;

  const size_t colb = (size_t)l16 * EPL;
  int j = 0;

  if (EPL == 8) {
    if (degc >= 8) {
      uint2 swb[8]; uint4 ub[8];
#pragma unroll
      for (int g = 0; g < 8; g++) swb[g] = swL[grp][g];
#pragma unroll
      for (int g = 0; g < 8; g++) ub[g] = *(const uint4*)(Hb + (size_t)swb[g].x * DOUT + colb);
      for (j = 8; j + 8 <= degc; j += 8) {
        uint2 swn[8]; uint4 un[8];
#pragma unroll
        for (int g = 0; g < 8; g++) swn[g] = swL[grp][j + g];
#pragma unroll
        for (int g = 0; g < 8; g++) un[g] = *(const uint4*)(Hb + (size_t)swn[g].x * DOUT + colb);
#pragma unroll
        for (int g = 0; g < 8; g++) {
          const float w = __uint_as_float(swb[g].y);
          const unsigned int a[4] = {ub[g].x, ub[g].y, ub[g].z, ub[g].w};
#pragma unroll
          for (int k = 0; k < 4; k++) {
            acc[2*k]   += __uint_as_float(a[k] << 16) * w;
            acc[2*k+1] += __uint_as_float(a[k] & 0xffff0000u) * w;
          }
        }
#pragma unroll
        for (int g = 0; g < 8; g++) { swb[g] = swn[g]; ub[g] = un[g]; }
      }
#pragma unroll
      for (int g = 0; g < 8; g++) {
        const float w = __uint_as_float(swb[g].y);
        const unsigned int a[4] = {ub[g].x, ub[g].y, ub[g].z, ub[g].w};
#pragma unroll
        for (int k = 0; k < 4; k++) {
          acc[2*k]   += __uint_as_float(a[k] << 16) * w;
          acc[2*k+1] += __uint_as_float(a[k] & 0xffff0000u) * w;
        }
      }
    }
  } else {
    if (degc >= 8) {
      uint2 swb[8]; uint2 ub[8];
#pragma unroll
      for (int g = 0; g < 8; g++) swb[g] = swL[grp][g];
#pragma unroll
      for (int g = 0; g < 8; g++) ub[g] = *(const uint2*)(Hb + (size_t)swb[g].x * DOUT + colb);
      for (j = 8; j + 8 <= degc; j += 8) {
        uint2 swn[8]; uint2 un[8];
#pragma unroll
        for (int g = 0; g < 8; g++) swn[g] = swL[grp][j + g];
#pragma unroll
        for (int g = 0; g < 8; g++) un[g] = *(const uint2*)(Hb + (size_t)swn[g].x * DOUT + colb);
#pragma unroll
        for (int g = 0; g < 8; g++) {
          const float w = __uint_as_float(swb[g].y);
          const unsigned int a[2] = {ub[g].x, ub[g].y};
#pragma unroll
          for (int k = 0; k < 2; k++) {
            acc[2*k]   += __uint_as_float(a[k] << 16) * w;
            acc[2*k+1] += __uint_as_float(a[k] & 0xffff0000u) * w;
          }
        }
#pragma unroll
        for (int g = 0; g < 8; g++) { swb[g] = swn[g]; ub[g] = un[g]; }
      }
#pragma unroll
      for (int g = 0; g < 8; g++) {
        const float w = __uint_as_float(swb[g].y);
        const unsigned int a[2] = {ub[g].x, ub[g].y};
#pragma unroll
        for (int k = 0; k < 2; k++) {
          acc[2*k]   += __uint_as_float(a[k] << 16) * w;
          acc[2*k+1] += __uint_as_float(a[k] & 0xffff0000u) * w;
        }
      }
    }
  }
  // remaining edges (<8 left)
  for (; j < degc; j++) {
    const uint2 sw = swL[grp][j];
    const float w = __uint_as_float(sw.y);
    const unsigned short* pp = Hb + (size_t)sw.x * DOUT + colb;
#pragma unroll
    for (int k = 0; k < EPL / 2; k++) {
      const unsigned int u = ((const unsigned int*)pp)[k];
      acc[2*k]   += __uint_as_float(u << 16) * w;
      acc[2*k+1] += __uint_as_float(u & 0xffff0000u) * w;
    }
  }
  // overflow edges (deg > CAP): recompute w from global (rare)
  for (j = CAP; j < deg; j++) {
    const int s = srcs[r0 + j];
    const float w = __expf(lrelu(Ss[s] + sd) - m);
    const unsigned short* pp = Hb + (size_t)s * DOUT + colb;
#pragma unroll
    for (int k = 0; k < EPL / 2; k++) {
      const unsigned int u = ((const unsigned int*)pp)[k];
      acc[2*k]   += __uint_as_float(u << 16) * w;
      acc[2*k+1] += __uint_as_float(u & 0xffff0000u) * w;
    }
  }
  // self contribution
  {
    const unsigned short* pp = Hb + (size_t)node * DOUT + colb;
#pragma unroll
    for (int k = 0; k < EPL / 2; k++) {
      const unsigned int u = ((const unsigned int*)pp)[k];
      acc[2*k]   += __uint_as_float(u << 16) * wself;
      acc[2*k+1] += __uint_as_float(u & 0xffff0000u) * wself;
    }
  }

  float o[EPL];
#pragma unroll
  for (int k = 0; k < EPL; k++) o[k] = acc[k] * inv + b[colb + k];
  if (OBF) {
    if (EPL == 8) {
      uint4 u;
      u.x = f2bf(o[0]) | (f2bf(o[1]) << 16);
      u.y = f2bf(o[2]) | (f2bf(o[3]) << 16);
      u.z = f2bf(o[4]) | (f2bf(o[5]) << 16);
      u.w = f2bf(o[6]) | (f2bf(o[7]) << 16);
      *(uint4*)(outb + (size_t)node * DOUT + colb) = u;
    } else {
      uint2 u;
      u.x = f2bf(o[0]) | (f2bf(o[1]) << 16);
      u.y = f2bf(o[2]) | (f2bf(o[3]) << 16);
      *(uint2*)(outb + (size_t)node * DOUT + colb) = u;
    }
  } else {
    float* op = out + (size_t)node * DOUT + colb;
#pragma unroll
    for (int k = 0; k < EPL; k += 4)
      *(float4*)(op + k) = make_float4(o[k], o[k+1], o[k+2], o[k+3]);
  }
}

// column-wise mean over N rows of a [N,64] matrix
__global__ void mean64(const float* __restrict__ Hf, float* __restrict__ out, int N, float scale) {
  __shared__ float sm[256];
  const int col = threadIdx.x & 63;
  const int seg = threadIdx.x >> 6;
  const int stride = gridDim.x * 4;
  float s = 0.f;
  for (int n = blockIdx.x * 4 + seg; n < N; n += stride) s += Hf[(size_t)n * 64 + col];
  sm[threadIdx.x] = s;
  __syncthreads();
  if (seg == 0) {
    float tot = sm[col] + sm[64 + col] + sm[128 + col] + sm[192 + col];
    atomAddF(&out[col], tot * scale);
  }
}

extern "C" void kernel_launch(void* const* d_in, const int* in_sizes, int n_in,
                              void* d_out, int out_size, void* d_ws, size_t ws_size,
                              hipStream_t stream) {
  const float* x   = (const float*)d_in[0];
  const int*   ei  = (const int*)d_in[1];
  const float* W1  = (const float*)d_in[2];
  const float* as1 = (const float*)d_in[3];
  const float* ad1 = (const float*)d_in[4];
  const float* b1  = (const float*)d_in[5];
  const float* W2  = (const float*)d_in[6];
  const float* as2 = (const float*)d_in[7];
  const float* ad2 = (const float*)d_in[8];
  const float* b2  = (const float*)d_in[9];
  const float* W3  = (const float*)d_in[10];
  const float* as3 = (const float*)d_in[11];
  const float* ad3 = (const float*)d_in[12];
  const float* b3  = (const float*)d_in[13];

  const int N = in_sizes[0] / 128;
  const int E = in_sizes[1] / 2;
  const int* src  = ei;
  const int* dstv = ei + E;
  const int RG = ceil_div(N, 64);
  const int NBA = ceil_div(E, TILE);
  const int NBUK = ceil_div(N, 1 << BKSH);

  float* p = (float*)d_ws;
  float* bufA = p; p += (size_t)N * 64;
  float* SsSd = p; p += (size_t)2 * N;
  float* Ss = SsSd, *Sd = SsSd + N;
  unsigned short* Xb = (unsigned short*)p; p += (size_t)N * 64;
  unsigned short* Hb = (unsigned short*)p; p += (size_t)N * 64;
  unsigned short* Wt1 = (unsigned short*)p; p += 128 * 128 / 2;
  unsigned short* Wt2 = (unsigned short*)p; p += 128 * 128 / 2;
  unsigned short* Wt3 = (unsigned short*)p; p += 128 * 64 / 2;
  int* ip = (int*)p;
  int* rowptr     = ip; ip += N + 1;
  int* bh         = ip; ip += (size_t)NBA * NBUK;
  int* tot        = ip; ip += NBUK;
  int* bucketBase = ip; ip += NBUK + 1;
  unsigned int* pairs = (unsigned int*)ip; ip += E;
  int* srcs       = ip; ip += E;

  // ---- CSR build (dst-major) via bucket sort, zero global atomics ----
  bucket_hist<<<NBA, 256, 0, stream>>>(dstv, bh, E, NBUK);
  col_scan<<<NBUK, 256, 0, stream>>>(bh, tot, NBA, NBUK);
  base_scan<<<1, 256, 0, stream>>>(tot, bucketBase, rowptr + N, NBUK, E);
  bucket_scatter<<<NBA, 256, 0, stream>>>(src, dstv, bh, bucketBase, pairs, E, NBUK);
  region_build<<<NBUK, 256, 0, stream>>>(pairs, bucketBase, rowptr, srcs, N);

  // ---- weight transposes (one launch) + input convert ----
  transpose_all<<<ceil_div(40960, 256), 256, 0, stream>>>(W1, W2, W3, Wt1, Wt2, Wt3);
  cvt_bf16<<<ceil_div((long long)N * 32, 256), 256, 0, stream>>>(x, Xb, N * 32);

  const int GG = ceil_div(N, 16);
  // ---- layer 1 ----
  hipMemsetAsync(SsSd, 0, (size_t)2 * N * sizeof(float), stream);
  gemm_mfma<128><<<ceil_div((long long)RG * 2, 4), 256, 0, stream>>>(Xb, Wt1, as1, ad1, Hb, Ss, Sd, N, RG);
  node_gather<128, true><<<GG, 256, 0, stream>>>(rowptr, srcs, Ss, Sd, Hb, b1, nullptr, Xb, N);
  // ---- layer 2 ----
  hipMemsetAsync(SsSd, 0, (size_t)2 * N * sizeof(float), stream);
  gemm_mfma<128><<<ceil_div((long long)RG * 2, 4), 256, 0, stream>>>(Xb, Wt2, as2, ad2, Hb, Ss, Sd, N, RG);
  node_gather<128, true><<<GG, 256, 0, stream>>>(rowptr, srcs, Ss, Sd, Hb, b2, nullptr, Xb, N);
  // ---- layer 3 ----
  hipMemsetAsync(SsSd, 0, (size_t)2 * N * sizeof(float), stream);
  gemm_mfma<64><<<ceil_div((long long)RG, 4), 256, 0, stream>>>(Xb, Wt3, as3, ad3, Hb, Ss, Sd, N, RG);
  node_gather<64, false><<<GG, 256, 0, stream>>>(rowptr, srcs, Ss, Sd, Hb, b3, bufA, nullptr, N);

  hipMemsetAsync(d_out, 0, 64 * sizeof(float), stream);
  mean64<<<256, 256, 0, stream>>>(bufA, (float*)d_out, N, 1.0f / (float)N);
}

// Round 11
// 437.687 us; speedup vs baseline: 1.0352x; 1.0352x over previous
//
#include <hip/hip_runtime.h>

static inline int ceil_div(long long a, long long b) { return (int)((a + b - 1) / b); }

typedef __attribute__((ext_vector_type(8))) short bf16x8;
typedef __attribute__((ext_vector_type(4))) float f32x4;

#define TILE 8192          // edges per bucket-pass block
#define BKSH 9             // bucket = dst >> 9  (512 dsts per bucket)

__device__ __forceinline__ float lrelu(float t) { return t > 0.f ? t : 0.2f * t; }

__device__ __forceinline__ void atomAddF(float* p, float v) {
  unsafeAtomicAdd(p, v);  // hardware global_atomic_add_f32
}

// float -> bf16 with round-to-nearest-even
__device__ __forceinline__ unsigned int f2bf(float f) {
  unsigned int u = __float_as_uint(f);
  unsigned int r = ((u >> 16) & 1u) + 0x7fffu;
  return (u + r) >> 16;
}

// ---------------- one-time converts ----------------
__global__ void cvt_bf16(const float* __restrict__ X, unsigned short* __restrict__ Xb, int n4) {
  int i = blockIdx.x * blockDim.x + threadIdx.x;
  if (i < n4) {
    const float4 v = ((const float4*)X)[i];
    uint2 o;
    o.x = f2bf(v.x) | (f2bf(v.y) << 16);
    o.y = f2bf(v.z) | (f2bf(v.w) << 16);
    ((uint2*)Xb)[i] = o;
  }
}

// all three weight transposes in one launch
__global__ void transpose_all(const float* __restrict__ W1, const float* __restrict__ W2,
                              const float* __restrict__ W3, unsigned short* __restrict__ Wt1,
                              unsigned short* __restrict__ Wt2, unsigned short* __restrict__ Wt3) {
  int idx = blockIdx.x * blockDim.x + threadIdx.x;
  const float* W; unsigned short* Wt; int local, DOUTv;
  if (idx < 16384)      { W = W1; Wt = Wt1; local = idx;          DOUTv = 128; }
  else if (idx < 32768) { W = W2; Wt = Wt2; local = idx - 16384;  DOUTv = 128; }
  else if (idx < 40960) { W = W3; Wt = Wt3; local = idx - 32768;  DOUTv = 64;  }
  else return;
  const int k = local / DOUTv, n = local % DOUTv;
  Wt[n * 128 + k] = (unsigned short)f2bf(W[local]);
}

// ---------------- MFMA GEMM + attention scores ----------------
// CG=2 (DOUT=128): the two column-waves of a row-group share a block and combine
// partial scores through LDS -> plain stores for Ss/Sd (no atomics, no pre-zeroing).
template<int DOUT>
__launch_bounds__(256)
__global__ void gemm_mfma(const unsigned short* __restrict__ Xb, const unsigned short* __restrict__ Wt,
                          const float* __restrict__ avs, const float* __restrict__ avd,
                          unsigned short* __restrict__ Hb, float* __restrict__ Ss,
                          float* __restrict__ Sd, int N, int RG) {
  constexpr int DIN = 128;
  constexpr int CG = DOUT / 64;     // 2 (DOUT=128) or 1 (DOUT=64)
  constexpr int RPB = 4 / CG;       // row-groups per block
  __shared__ float sps[RPB][2][64], spd[RPB][2][64];

  const int wv = threadIdx.x >> 6;        // 0..3
  const int rgl = wv / CG;
  const int cg  = wv % CG;
  const int rg = blockIdx.x * RPB + rgl;
  const bool active = rg < RG;
  const int lane = threadIdx.x & 63;
  const int l16 = lane & 15, quad = lane >> 4;
  const int row0 = rg * 64, colw0 = cg * 64;

  if (active) {
    int xoff[4], woff[4];
#pragma unroll
    for (int t = 0; t < 4; t++) {
      int m = row0 + t * 16 + l16; if (m > N - 1) m = N - 1;
      xoff[t] = m * DIN + quad * 8;
      woff[t] = (colw0 + t * 16 + l16) * DIN + quad * 8;
    }

    f32x4 acc[4][4];
#pragma unroll
    for (int a = 0; a < 4; a++)
#pragma unroll
      for (int c = 0; c < 4; c++) acc[a][c] = (f32x4)0.f;

#pragma unroll
    for (int kk = 0; kk < 4; kk++) {
      bf16x8 aw[4], bx[4];
#pragma unroll
      for (int t = 0; t < 4; t++) aw[t] = *(const bf16x8*)(Wt + woff[t] + kk * 32);
#pragma unroll
      for (int t = 0; t < 4; t++) bx[t] = *(const bf16x8*)(Xb + xoff[t] + kk * 32);
#pragma unroll
      for (int wt = 0; wt < 4; wt++)
#pragma unroll
        for (int xt = 0; xt < 4; xt++)
          acc[wt][xt] = __builtin_amdgcn_mfma_f32_16x16x32_bf16(aw[wt], bx[xt], acc[wt][xt], 0, 0, 0);
    }

    float4 af[4], df[4];
#pragma unroll
    for (int wt = 0; wt < 4; wt++) {
      af[wt] = *(const float4*)(avs + colw0 + wt * 16 + quad * 4);
      df[wt] = *(const float4*)(avd + colw0 + wt * 16 + quad * 4);
    }
#pragma unroll
    for (int xt = 0; xt < 4; xt++) {
      const int m = row0 + xt * 16 + l16;
      float ps = 0.f, pd = 0.f;
#pragma unroll
      for (int wt = 0; wt < 4; wt++) {
        const f32x4 c = acc[wt][xt];
        ps += c[0]*af[wt].x + c[1]*af[wt].y + c[2]*af[wt].z + c[3]*af[wt].w;
        pd += c[0]*df[wt].x + c[1]*df[wt].y + c[2]*df[wt].z + c[3]*df[wt].w;
      }
      ps += __shfl_xor(ps, 16); ps += __shfl_xor(ps, 32);
      pd += __shfl_xor(pd, 16); pd += __shfl_xor(pd, 32);
      if (quad == 0) {
        if (CG == 2) {
          sps[rgl][cg][xt * 16 + l16] = ps;
          spd[rgl][cg][xt * 16 + l16] = pd;
        } else if (m < N) {
          Ss[m] = ps; Sd[m] = pd;
        }
      }
      if (m < N) {
        unsigned short* hp = Hb + (size_t)m * DOUT + colw0 + quad * 4;
#pragma unroll
        for (int wt = 0; wt < 4; wt++) {
          const f32x4 c = acc[wt][xt];
          uint2 o;
          o.x = f2bf(c[0]) | (f2bf(c[1]) << 16);
          o.y = f2bf(c[2]) | (f2bf(c[3]) << 16);
          *(uint2*)(hp + wt * 16) = o;
        }
      }
    }
  }
  if (CG == 2) {
    __syncthreads();
    if (active && cg == 0) {
      const int m = row0 + lane;
      if (m < N) {
        Ss[m] = sps[rgl][0][lane] + sps[rgl][1][lane];
        Sd[m] = spd[rgl][0][lane] + spd[rgl][1][lane];
      }
    }
  }
}

// ---------------- CSR build: bucket sort, zero global atomics ----------------
__launch_bounds__(256)
__global__ void bucket_hist(const int* __restrict__ dstv, int* __restrict__ bh,
                            int E, int NBUK) {
  __shared__ int h[256];
  h[threadIdx.x] = 0;
  __syncthreads();
  const int base = blockIdx.x * TILE;
  const int end = min(E, base + TILE);
  for (int i = base + threadIdx.x; i < end; i += 256)
    atomicAdd(&h[dstv[i] >> BKSH], 1);
  __syncthreads();
  if (threadIdx.x < NBUK) bh[blockIdx.x * NBUK + threadIdx.x] = h[threadIdx.x];
}

__launch_bounds__(256)
__global__ void col_scan(int* __restrict__ bh, int* __restrict__ tot, int NBA, int NBUK) {
  __shared__ int sc[256];
  const int t = threadIdx.x;
  const int b = blockIdx.x;
  int carry = 0;
  for (int c0 = 0; c0 < NBA; c0 += 256) {
    const int idx = c0 + t;
    const int v = (idx < NBA) ? bh[idx * NBUK + b] : 0;
    sc[t] = v;
    __syncthreads();
    for (int off = 1; off < 256; off <<= 1) {
      int u = (t >= off) ? sc[t - off] : 0;
      __syncthreads();
      sc[t] += u;
      __syncthreads();
    }
    if (idx < NBA) bh[idx * NBUK + b] = carry + sc[t] - v;
    carry += sc[255];
    __syncthreads();
  }
  if (t == 0) tot[b] = carry;
}

__launch_bounds__(256)
__global__ void base_scan(const int* __restrict__ tot, int* __restrict__ bucketBase,
                          int* __restrict__ rowptr_N, int NBUK, int E) {
  __shared__ int sc[256];
  const int t = threadIdx.x;
  int carry = 0;
  for (int c0 = 0; c0 < NBUK; c0 += 256) {
    const int idx = c0 + t;
    const int v = (idx < NBUK) ? tot[idx] : 0;
    sc[t] = v;
    __syncthreads();
    for (int off = 1; off < 256; off <<= 1) {
      int u = (t >= off) ? sc[t - off] : 0;
      __syncthreads();
      sc[t] += u;
      __syncthreads();
    }
    if (idx < NBUK) bucketBase[idx] = carry + sc[t] - v;
    carry += sc[255];
    __syncthreads();
  }
  if (t == 0) { bucketBase[NBUK] = E; *rowptr_N = E; }
}

__launch_bounds__(256)
__global__ void bucket_scatter(const int* __restrict__ src, const int* __restrict__ dstv,
                               const int* __restrict__ bh, const int* __restrict__ bucketBase,
                               unsigned int* __restrict__ pairs, int E, int NBUK) {
  __shared__ int ofs[256];
  if (threadIdx.x < NBUK)
    ofs[threadIdx.x] = bh[blockIdx.x * NBUK + threadIdx.x] + bucketBase[threadIdx.x];
  __syncthreads();
  const int base = blockIdx.x * TILE;
  const int end = min(E, base + TILE);
  for (int i = base + threadIdx.x; i < end; i += 256) {
    const int d = dstv[i];
    const int pos = atomicAdd(&ofs[d >> BKSH], 1);
    pairs[pos] = ((unsigned int)src[i] << BKSH) | (unsigned int)(d & ((1 << BKSH) - 1));
  }
}

__launch_bounds__(256)
__global__ void region_build(const unsigned int* __restrict__ pairs,
                             const int* __restrict__ bucketBase,
                             int* __restrict__ rowptr, int* __restrict__ srcs, int N) {
  __shared__ int cnt[512], ofs[512], ps[256];
  const int t = threadIdx.x;
  const int r = blockIdx.x;
  const int p0 = bucketBase[r], p1 = bucketBase[r + 1];
  cnt[t] = 0; cnt[t + 256] = 0;
  __syncthreads();
  for (int i = p0 + t; i < p1; i += 256)
    atomicAdd(&cnt[pairs[i] & 511u], 1);
  __syncthreads();
  const int c0 = cnt[2 * t], c1 = cnt[2 * t + 1];
  const int pr = c0 + c1;
  ps[t] = pr;
  __syncthreads();
  for (int off = 1; off < 256; off <<= 1) {
    int v = (t >= off) ? ps[t - off] : 0;
    __syncthreads();
    ps[t] += v;
    __syncthreads();
  }
  const int pbase = ps[t] - pr;
  ofs[2 * t] = pbase; ofs[2 * t + 1] = pbase + c0;
  __syncthreads();
  {
    const int d0 = (r << BKSH) + t;
    if (d0 < N) rowptr[d0] = p0 + ofs[t];
    const int d1 = (r << BKSH) + t + 256;
    if (d1 < N) rowptr[d1] = p0 + ofs[t + 256];
  }
  __syncthreads();
  for (int i = p0 + t; i < p1; i += 256) {
    const unsigned int w = pairs[i];
    const int pos = atomicAdd(&ofs[w & 511u], 1);
    srcs[p0 + pos] = (int)(w >> BKSH);
  }
}

// ---------------- fused per-dst gather: single-pass, no segment-max ----------------
// exp(e)/sum(exp(e)) == exp(e-m)/sum(exp(e-m)); scores are O(10) so f32 exp is safe.
// 16 lanes per node, 16 nodes per block. Per 16-edge chunk: compute (s,w) per lane,
// stash in a 16-slot LDS buffer (same wave -> NO barriers), consume immediately with
// 4-deep row loads. One pass over edges; no CAP/overflow machinery.
template<int DOUT, bool OBF>
__launch_bounds__(256)
__global__ void node_gather(const int* __restrict__ rowptr, const int* __restrict__ srcs,
                            const float* __restrict__ Ss, const float* __restrict__ Sd,
                            const unsigned short* __restrict__ Hb, const float* __restrict__ b,
                            float* __restrict__ out, unsigned short* __restrict__ outb, int N) {
  constexpr int EPL = DOUT / 16;          // bf16 elems per lane (8 or 4)
  __shared__ uint2 swL[16][18];           // 16 slots + pad (stride 36 words: banks disjoint)

  const int l16 = threadIdx.x & 15;
  const int grp = threadIdx.x >> 4;
  const int node = blockIdx.x * 16 + grp;
  if (node >= N) return;

  const int r0 = rowptr[node], r1 = rowptr[node + 1];
  const int deg = r1 - r0;
  const float sd = Sd[node];
  const float wself = __expf(lrelu(Ss[node] + sd));

  float acc[EPL];
#pragma unroll
  for (int k = 0; k < EPL; k++) acc[k] = 0.f;
  float lsum = 0.f;
  const size_t colb = (size_t)l16 * EPL;

  for (int j0 = 0; j0 < deg; j0 += 16) {
    const int idx = j0 + l16;
    int s = node; float w = 0.f;
    if (idx < deg) {
      s = srcs[r0 + idx];
      w = __expf(lrelu(Ss[s] + sd));
    }
    lsum += w;
    swL[grp][l16] = make_uint2((unsigned)s, __float_as_uint(w));
    const int cnt = min(16, deg - j0);
    int t = 0;
    for (; t + 4 <= cnt; t += 4) {
      const uint2 sw0 = swL[grp][t],     sw1 = swL[grp][t + 1];
      const uint2 sw2 = swL[grp][t + 2], sw3 = swL[grp][t + 3];
      const float w0 = __uint_as_float(sw0.y), w1 = __uint_as_float(sw1.y);
      const float w2 = __uint_as_float(sw2.y), w3 = __uint_as_float(sw3.y);
      if (EPL == 8) {
        const uint4 u0 = *(const uint4*)(Hb + (size_t)sw0.x * DOUT + colb);
        const uint4 u1 = *(const uint4*)(Hb + (size_t)sw1.x * DOUT + colb);
        const uint4 u2 = *(const uint4*)(Hb + (size_t)sw2.x * DOUT + colb);
        const uint4 u3 = *(const uint4*)(Hb + (size_t)sw3.x * DOUT + colb);
        const unsigned int a0[4] = {u0.x,u0.y,u0.z,u0.w}, a1[4] = {u1.x,u1.y,u1.z,u1.w};
        const unsigned int a2[4] = {u2.x,u2.y,u2.z,u2.w}, a3[4] = {u3.x,u3.y,u3.z,u3.w};
#pragma unroll
        for (int k = 0; k < 4; k++) {
          acc[2*k]   += __uint_as_float(a0[k] << 16) * w0 + __uint_as_float(a1[k] << 16) * w1
                      + __uint_as_float(a2[k] << 16) * w2 + __uint_as_float(a3[k] << 16) * w3;
          acc[2*k+1] += __uint_as_float(a0[k] & 0xffff0000u) * w0 + __uint_as_float(a1[k] & 0xffff0000u) * w1
                      + __uint_as_float(a2[k] & 0xffff0000u) * w2 + __uint_as_float(a3[k] & 0xffff0000u) * w3;
        }
      } else {
        const uint2 u0 = *(const uint2*)(Hb + (size_t)sw0.x * DOUT + colb);
        const uint2 u1 = *(const uint2*)(Hb + (size_t)sw1.x * DOUT + colb);
        const uint2 u2 = *(const uint2*)(Hb + (size_t)sw2.x * DOUT + colb);
        const uint2 u3 = *(const uint2*)(Hb + (size_t)sw3.x * DOUT + colb);
        const unsigned int a0[2] = {u0.x,u0.y}, a1[2] = {u1.x,u1.y};
        const unsigned int a2[2] = {u2.x,u2.y}, a3[2] = {u3.x,u3.y};
#pragma unroll
        for (int k = 0; k < 2; k++) {
          acc[2*k]   += __uint_as_float(a0[k] << 16) * w0 + __uint_as_float(a1[k] << 16) * w1
                      + __uint_as_float(a2[k] << 16) * w2 + __uint_as_float(a3[k] << 16) * w3;
          acc[2*k+1] += __uint_as_float(a0[k] & 0xffff0000u) * w0 + __uint_as_float(a1[k] & 0xffff0000u) * w1
                      + __uint_as_float(a2[k] & 0xffff0000u) * w2 + __uint_as_float(a3[k] & 0xffff0000u) * w3;
        }
      }
    }
    for (; t < cnt; t++) {
      const uint2 sw = swL[grp][t];
      const float w0 = __uint_as_float(sw.y);
      const unsigned short* pp = Hb + (size_t)sw.x * DOUT + colb;
#pragma unroll
      for (int k = 0; k < EPL / 2; k++) {
        const unsigned int u = ((const unsigned int*)pp)[k];
        acc[2*k]   += __uint_as_float(u << 16) * w0;
        acc[2*k+1] += __uint_as_float(u & 0xffff0000u) * w0;
      }
    }
  }

  // reduce edge-weight sum across the 16-lane group
#pragma unroll
  for (int off = 8; off; off >>= 1) lsum += __shfl_xor(lsum, off);

  // self contribution
  {
    const unsigned short* pp = Hb + (size_t)node * DOUT + colb;
#pragma unroll
    for (int k = 0; k < EPL / 2; k++) {
      const unsigned int u = ((const unsigned int*)pp)[k];
      acc[2*k]   += __uint_as_float(u << 16) * wself;
      acc[2*k+1] += __uint_as_float(u & 0xffff0000u) * wself;
    }
  }
  const float inv = 1.f / (lsum + wself);

  float o[EPL];
#pragma unroll
  for (int k = 0; k < EPL; k++) o[k] = acc[k] * inv + b[colb + k];
  if (OBF) {
    if (EPL == 8) {
      uint4 u;
      u.x = f2bf(o[0]) | (f2bf(o[1]) << 16);
      u.y = f2bf(o[2]) | (f2bf(o[3]) << 16);
      u.z = f2bf(o[4]) | (f2bf(o[5]) << 16);
      u.w = f2bf(o[6]) | (f2bf(o[7]) << 16);
      *(uint4*)(outb + (size_t)node * DOUT + colb) = u;
    } else {
      uint2 u;
      u.x = f2bf(o[0]) | (f2bf(o[1]) << 16);
      u.y = f2bf(o[2]) | (f2bf(o[3]) << 16);
      *(uint2*)(outb + (size_t)node * DOUT + colb) = u;
    }
  } else {
    float* op = out + (size_t)node * DOUT + colb;
#pragma unroll
    for (int k = 0; k < EPL; k += 4)
      *(float4*)(op + k) = make_float4(o[k], o[k+1], o[k+2], o[k+3]);
  }
}

// column-wise mean over N rows of a [N,64] matrix
__global__ void mean64(const float* __restrict__ Hf, float* __restrict__ out, int N, float scale) {
  __shared__ float sm[256];
  const int col = threadIdx.x & 63;
  const int seg = threadIdx.x >> 6;
  const int stride = gridDim.x * 4;
  float s = 0.f;
  for (int n = blockIdx.x * 4 + seg; n < N; n += stride) s += Hf[(size_t)n * 64 + col];
  sm[threadIdx.x] = s;
  __syncthreads();
  if (seg == 0) {
    float tot = sm[col] + sm[64 + col] + sm[128 + col] + sm[192 + col];
    atomAddF(&out[col], tot * scale);
  }
}

extern "C" void kernel_launch(void* const* d_in, const int* in_sizes, int n_in,
                              void* d_out, int out_size, void* d_ws, size_t ws_size,
                              hipStream_t stream) {
  const float* x   = (const float*)d_in[0];
  const int*   ei  = (const int*)d_in[1];
  const float* W1  = (const float*)d_in[2];
  const float* as1 = (const float*)d_in[3];
  const float* ad1 = (const float*)d_in[4];
  const float* b1  = (const float*)d_in[5];
  const float* W2  = (const float*)d_in[6];
  const float* as2 = (const float*)d_in[7];
  const float* ad2 = (const float*)d_in[8];
  const float* b2  = (const float*)d_in[9];
  const float* W3  = (const float*)d_in[10];
  const float* as3 = (const float*)d_in[11];
  const float* ad3 = (const float*)d_in[12];
  const float* b3  = (const float*)d_in[13];

  const int N = in_sizes[0] / 128;
  const int E = in_sizes[1] / 2;
  const int* src  = ei;
  const int* dstv = ei + E;
  const int RG = ceil_div(N, 64);
  const int NBA = ceil_div(E, TILE);
  const int NBUK = ceil_div(N, 1 << BKSH);

  float* p = (float*)d_ws;
  float* bufA = p; p += (size_t)N * 64;
  float* SsSd = p; p += (size_t)2 * N;
  float* Ss = SsSd, *Sd = SsSd + N;
  unsigned short* Xb = (unsigned short*)p; p += (size_t)N * 64;
  unsigned short* Hb = (unsigned short*)p; p += (size_t)N * 64;
  unsigned short* Wt1 = (unsigned short*)p; p += 128 * 128 / 2;
  unsigned short* Wt2 = (unsigned short*)p; p += 128 * 128 / 2;
  unsigned short* Wt3 = (unsigned short*)p; p += 128 * 64 / 2;
  int* ip = (int*)p;
  int* rowptr     = ip; ip += N + 1;
  int* bh         = ip; ip += (size_t)NBA * NBUK;
  int* tot        = ip; ip += NBUK;
  int* bucketBase = ip; ip += NBUK + 1;
  unsigned int* pairs = (unsigned int*)ip; ip += E;
  int* srcs       = ip; ip += E;

  // ---- CSR build (dst-major) via bucket sort, zero global atomics ----
  bucket_hist<<<NBA, 256, 0, stream>>>(dstv, bh, E, NBUK);
  col_scan<<<NBUK, 256, 0, stream>>>(bh, tot, NBA, NBUK);
  base_scan<<<1, 256, 0, stream>>>(tot, bucketBase, rowptr + N, NBUK, E);
  bucket_scatter<<<NBA, 256, 0, stream>>>(src, dstv, bh, bucketBase, pairs, E, NBUK);
  region_build<<<NBUK, 256, 0, stream>>>(pairs, bucketBase, rowptr, srcs, N);

  // ---- weight transposes (one launch) + input convert ----
  transpose_all<<<ceil_div(40960, 256), 256, 0, stream>>>(W1, W2, W3, Wt1, Wt2, Wt3);
  cvt_bf16<<<ceil_div((long long)N * 32, 256), 256, 0, stream>>>(x, Xb, N * 32);

  const int GG = ceil_div(N, 16);
  // ---- layer 1 ----
  gemm_mfma<128><<<ceil_div(RG, 2), 256, 0, stream>>>(Xb, Wt1, as1, ad1, Hb, Ss, Sd, N, RG);
  node_gather<128, true><<<GG, 256, 0, stream>>>(rowptr, srcs, Ss, Sd, Hb, b1, nullptr, Xb, N);
  // ---- layer 2 ----
  gemm_mfma<128><<<ceil_div(RG, 2), 256, 0, stream>>>(Xb, Wt2, as2, ad2, Hb, Ss, Sd, N, RG);
  node_gather<128, true><<<GG, 256, 0, stream>>>(rowptr, srcs, Ss, Sd, Hb, b2, nullptr, Xb, N);
  // ---- layer 3 ----
  gemm_mfma<64><<<ceil_div(RG, 4), 256, 0, stream>>>(Xb, Wt3, as3, ad3, Hb, Ss, Sd, N, RG);
  node_gather<64, false><<<GG, 256, 0, stream>>>(rowptr, srcs, Ss, Sd, Hb, b3, bufA, nullptr, N);

  hipMemsetAsync(d_out, 0, 64 * sizeof(float), stream);
  mean64<<<256, 256, 0, stream>>>(bufA, (float*)d_out, N, 1.0f / (float)N);
}